// Round 10
// baseline (117.101 us; speedup 1.0000x reference)
//
#include <hip/hip_runtime.h>
#include <math.h>

#define NEG_BIG -1.0e30f
#define BSHIFT 8                 // bucket = 256 target-node ids
#define MAXB 256

typedef __attribute__((ext_vector_type(8))) short short8v;   // 8 bf16
typedef __attribute__((ext_vector_type(4))) float f32x4;

__device__ __forceinline__ ushort f2bf(float f) {
  unsigned u = __float_as_uint(f);
  unsigned r = (u + 0x7fffu + ((u >> 16) & 1u)) >> 16;  // round-to-nearest-even
  return (ushort)r;
}
__device__ __forceinline__ float bf_lo(unsigned u) { return __uint_as_float(u << 16); }
__device__ __forceinline__ float bf_hi(unsigned u) { return __uint_as_float(u & 0xffff0000u); }

// ---------- zero bucket_count + done (1 block) ----------
__global__ void zero_k(int* __restrict__ bucket_count, int* __restrict__ done) {
  int t = (int)threadIdx.x;
  if (t < MAXB) bucket_count[t] = 0;
  if (t == 0) *done = 0;
}

// ---------- convert + pack (col<<16)|row + LDS bucket histogram; last block scans ----------
// NOTE: requires N < 65536; N = 50000 here.
__global__ __launch_bounds__(256) void histB_k(const void* __restrict__ ei, int E,
                                               unsigned* __restrict__ packed,
                                               int* __restrict__ bucket_count,
                                               int* __restrict__ done,
                                               int* __restrict__ bcur,
                                               int* __restrict__ bucket_base, int nblocks) {
  __shared__ int lh[MAXB];
  __shared__ int wsum[4];
  __shared__ int last;
  int tid = (int)threadIdx.x;
  lh[tid] = 0;
  __syncthreads();

  const int* p32 = (const int*)ei;
  bool is64 = true;
#pragma unroll
  for (int i = 0; i < 32; ++i) is64 = is64 && (p32[2 * i + 1] == 0);
  const long long* p64 = (const long long*)ei;
  int stride = gridDim.x * 256;
  for (int e = blockIdx.x * 256 + tid; e < E; e += stride) {
    int r, c;
    if (is64) { r = (int)p64[e]; c = (int)p64[E + e]; }
    else      { r = p32[e];      c = p32[E + e]; }
    packed[e] = ((unsigned)c << 16) | (unsigned)r;
    atomicAdd(&lh[c >> BSHIFT], 1);
  }
  __syncthreads();
  if (lh[tid]) atomicAdd(&bucket_count[tid], lh[tid]);
  __threadfence();
  if (tid == 0) {
    int old = atomicAdd(done, 1);
    last = (old == nblocks - 1);
  }
  __syncthreads();
  if (!last) return;
  __threadfence();

  int lane = tid & 63, wid = tid >> 6;
  int v = atomicAdd(&bucket_count[tid], 0);
  int x = v;
#pragma unroll
  for (int off = 1; off < 64; off <<= 1) {
    int t = __shfl_up(x, off);
    if (lane >= off) x += t;
  }
  if (lane == 63) wsum[wid] = x;
  __syncthreads();
  int woff = 0;
  for (int w = 0; w < wid; ++w) woff += wsum[w];
  int excl = woff + x - v;
  bcur[tid] = excl;
  bucket_base[tid] = excl;
  if (tid == 255) bucket_base[256] = excl + v;
}

// ---------- Wh = h @ W via MFMA bf16, fragment-layout LDS staging ----------
// block = 256 thr = 4 waves; 64 rows/block; W packed to LDS in-kernel.
// k-map (applied identically to A and B, so result is layout-invariant):
//   k = kk*32 + lg*8 + i,  lane l = lg*16 + lm
__global__ __launch_bounds__(256) void gemm_wh(const float* __restrict__ h,
                                               const float* __restrict__ W,
                                               const float* __restrict__ a,
                                               ushort* __restrict__ Whb,
                                               float* __restrict__ asrc,
                                               float* __restrict__ adst, int N) {
  __shared__ ushort Af[4 * 4 * 64 * 8];   // [w][kk][lane][8] : 16 KB
  __shared__ ushort Bf[4 * 8 * 64 * 8];   // [kk][n0][lane][8]: 32 KB
  int tid = (int)threadIdx.x;
  int r0 = blockIdx.x * 64;

  // stage W -> Bf (coalesced float4 reads; fragment-slot writes)
  for (int idx = tid; idx < 4096; idx += 256) {
    float4 v = ((const float4*)W)[idx];
    int k = idx >> 5;            // W row (k index)
    int n4 = (idx & 31) * 4;     // first of 4 consecutive n
    int kk = k >> 5, lg = (k & 31) >> 3, i = k & 7;
    int n0 = n4 >> 4, lm0 = n4 & 15;
    int slot = ((kk * 8 + n0) * 64 + lg * 16 + lm0) * 8 + i;
    Bf[slot]      = f2bf(v.x);
    Bf[slot + 8]  = f2bf(v.y);
    Bf[slot + 16] = f2bf(v.z);
    Bf[slot + 24] = f2bf(v.w);
  }

  // stage h rows r0..r0+63 -> Af (coalesced float4 reads; ushort4 slot writes)
  for (int idx = tid; idx < 2048; idx += 256) {
    int row = idx >> 5;
    int c4 = idx & 31;
    int gr = r0 + row;
    float4 v = (gr < N) ? ((const float4*)h)[(size_t)gr * 32 + c4]
                        : make_float4(0.f, 0.f, 0.f, 0.f);
    int c0 = c4 * 4;
    int w = row >> 4, lm = row & 15;
    int kk = c0 >> 5, lg = (c0 & 31) >> 3, i0 = c0 & 7;  // i0 in {0,4}
    int slotbase = ((w * 4 + kk) * 64 + lg * 16 + lm) * 8 + i0;
    ushort4 pk;
    pk.x = f2bf(v.x); pk.y = f2bf(v.y); pk.z = f2bf(v.z); pk.w = f2bf(v.w);
    *(ushort4*)&Af[slotbase] = pk;
  }
  __syncthreads();

  int w = tid >> 6;
  int l = tid & 63;
  int lg = l >> 4;
  int lm = l & 15;
  int r0w = r0 + 16 * w;
  const short8v* Af8 = (const short8v*)Af;
  const short8v* Bf8 = (const short8v*)Bf;

  float as_v[8], ad_v[8];
#pragma unroll
  for (int n0 = 0; n0 < 8; ++n0) {
    as_v[n0] = a[n0 * 16 + lm];
    ad_v[n0] = a[128 + n0 * 16 + lm];
  }

  f32x4 acc[8];
#pragma unroll
  for (int n0 = 0; n0 < 8; ++n0) acc[n0] = (f32x4){0.f, 0.f, 0.f, 0.f};

#pragma unroll
  for (int kk = 0; kk < 4; ++kk) {
    short8v av = Af8[(w * 4 + kk) * 64 + l];
#pragma unroll
    for (int n0 = 0; n0 < 8; ++n0) {
      short8v bv = Bf8[(kk * 8 + n0) * 64 + l];
      acc[n0] = __builtin_amdgcn_mfma_f32_16x16x32_bf16(av, bv, acc[n0], 0, 0, 0);
    }
  }

  // store Whb (bf16). D layout: col = n0*16+lm, local row = lg*4+reg
#pragma unroll
  for (int reg = 0; reg < 4; ++reg) {
    int r = r0w + lg * 4 + reg;
    if (r < N) {
      ushort* dst = Whb + (size_t)r * 128;
#pragma unroll
      for (int n0 = 0; n0 < 8; ++n0) dst[n0 * 16 + lm] = f2bf(acc[n0][reg]);
    }
  }

  // fused alpha: reduce over the 16 lm lanes
#pragma unroll
  for (int reg = 0; reg < 4; ++reg) {
    float ps = 0.f, pd = 0.f;
#pragma unroll
    for (int n0 = 0; n0 < 8; ++n0) {
      ps += acc[n0][reg] * as_v[n0];
      pd += acc[n0][reg] * ad_v[n0];
    }
#pragma unroll
    for (int off = 1; off < 16; off <<= 1) {
      ps += __shfl_xor(ps, off);
      pd += __shfl_xor(pd, off);
    }
    int r = r0w + lg * 4 + reg;
    if (lm == 0 && r < N) { asrc[r] = ps; adst[r] = pd; }
  }
}

// ---------- phase 1 sort: coarse-bin packed records by col bucket ----------
#define TILE 4096
__global__ __launch_bounds__(1024) void bin_k(const unsigned* __restrict__ packed,
                                              int* __restrict__ bcur,
                                              unsigned* __restrict__ bin_buf, int E) {
  __shared__ int lhist[MAXB];
  __shared__ int lbase[MAXB];
  int tid = (int)threadIdx.x;
  int t0 = blockIdx.x * TILE;

  if (tid < MAXB) lhist[tid] = 0;
  __syncthreads();

  unsigned rec[4];
  int rb[4], rr[4];
#pragma unroll
  for (int k = 0; k < 4; ++k) {
    int i = t0 + tid + k * 1024;
    rb[k] = -1;
    if (i < E) {
      rec[k] = packed[i];
      rb[k] = (int)(rec[k] >> (16 + BSHIFT));
      rr[k] = atomicAdd(&lhist[rb[k]], 1);
    }
  }
  __syncthreads();
  if (tid < MAXB) lbase[tid] = lhist[tid] ? atomicAdd(&bcur[tid], lhist[tid]) : 0;
  __syncthreads();
#pragma unroll
  for (int k = 0; k < 4; ++k) {
    if (rb[k] >= 0) bin_buf[lbase[rb[k]] + rr[k]] = rec[k];
  }
}

// ---------- phase 2 sort: bucket-local col hist+scan -> rowptr + permute ----------
__global__ __launch_bounds__(1024) void perm3_k(const unsigned* __restrict__ bin_buf,
                                                const int* __restrict__ bucket_base,
                                                int* __restrict__ rowptr,
                                                ushort* __restrict__ row_sorted,
                                                int N, int nbuckets) {
  __shared__ int hist[MAXB];
  __shared__ int cur[MAXB];
  __shared__ int wsum[16];
  int b = blockIdx.x;
  int tid = (int)threadIdx.x;
  int c0 = b << BSHIFT;
  int ncol = min(MAXB, N - c0);
  int e0 = bucket_base[b], e1 = bucket_base[b + 1];

  if (tid < MAXB) hist[tid] = 0;
  __syncthreads();
  for (int i = e0 + tid; i < e1; i += 1024)
    atomicAdd(&hist[(bin_buf[i] >> 16) - c0], 1);
  __syncthreads();

  int lane = tid & 63, wid = tid >> 6;
  int v = (tid < MAXB) ? hist[tid] : 0;
  int x = v;
#pragma unroll
  for (int off = 1; off < 64; off <<= 1) {
    int t = __shfl_up(x, off);
    if (lane >= off) x += t;
  }
  if (lane == 63) wsum[wid] = x;
  __syncthreads();
  if (tid < MAXB) {
    int woff = 0;
    for (int w = 0; w < wid; ++w) woff += wsum[w];
    int excl = woff + x - v;
    cur[tid] = e0 + excl;
    if (tid < ncol) rowptr[c0 + tid] = e0 + excl;
  }
  if (b == nbuckets - 1 && tid == 0) rowptr[N] = e1;
  __syncthreads();

  for (int i = e0 + tid; i < e1; i += 1024) {
    unsigned rec = bin_buf[i];
    int p = atomicAdd(&cur[(rec >> 16) - c0], 1);
    row_sorted[p] = (ushort)(rec & 0xffffu);
  }
}

// ---------- fused softmax + aggregation + ELU (one wave per node, no LDS) ----------
__global__ __launch_bounds__(256) void softagg_k(const int* __restrict__ rowptr,
                                                 const ushort* __restrict__ row_sorted,
                                                 const float* __restrict__ asrc,
                                                 const float* __restrict__ adst,
                                                 const ushort* __restrict__ Whb,
                                                 float* __restrict__ out, int N) {
  int node = blockIdx.x * 4 + ((int)threadIdx.x >> 6);
  if (node >= N) return;
  int lane = (int)threadIdx.x & 63;
  int beg = rowptr[node], end = rowptr[node + 1];
  int deg = end - beg;
  float adc = adst[node];
  float ax = 0.f, ay = 0.f;

  if (deg <= 64) {
    // fast path: one edge per lane, softmax entirely in registers
    int r = 0;
    float v = NEG_BIG;
    if (lane < deg) {
      r = row_sorted[beg + lane];
      v = asrc[r] + adc;
      v = (v >= 0.f) ? v : 0.2f * v;
    }
    float m = v;
#pragma unroll
    for (int off = 32; off > 0; off >>= 1) m = fmaxf(m, __shfl_xor(m, off));
    float e = (lane < deg) ? expf(v - m) : 0.f;
    float s = e;
#pragma unroll
    for (int off = 32; off > 0; off >>= 1) s += __shfl_xor(s, off);
    float w = e / (s + 1e-16f);

    // phase 2: lanes become features; pull (w_j, r_j) from lane j, 8-deep MLP
    int j = 0;
    for (; j + 7 < deg; j += 8) {
      float wv[8];
      int rv[8];
#pragma unroll
      for (int q = 0; q < 8; ++q) { wv[q] = __shfl(w, j + q); rv[q] = __shfl(r, j + q); }
      unsigned u[8];
#pragma unroll
      for (int q = 0; q < 8; ++q) u[q] = ((const unsigned*)(Whb + (size_t)rv[q] * 128))[lane];
#pragma unroll
      for (int q = 0; q < 8; ++q) { ax += wv[q] * bf_lo(u[q]); ay += wv[q] * bf_hi(u[q]); }
    }
    for (; j < deg; ++j) {
      float wj = __shfl(w, j);
      int rj = __shfl(r, j);
      unsigned u = ((const unsigned*)(Whb + (size_t)rj * 128))[lane];
      ax += wj * bf_lo(u); ay += wj * bf_hi(u);
    }
  } else {
    // slow path (deg > 64): online softmax + recompute weights
    float m = NEG_BIG, s = 0.f;
    for (int i = beg + lane; i < end; i += 64) {
      float v = asrc[row_sorted[i]] + adc;
      v = (v >= 0.f) ? v : 0.2f * v;
      if (v > m) { s = s * expf(m - v) + 1.f; m = v; }
      else       { s += expf(v - m); }
    }
#pragma unroll
    for (int off = 32; off > 0; off >>= 1) {
      float mo = __shfl_xor(m, off);
      float so = __shfl_xor(s, off);
      float M = fmaxf(m, mo);
      s = s * expf(m - M) + so * expf(mo - M);
      m = M;
    }
    float inv = 1.f / (s + 1e-16f);
    for (int i = beg; i < end; ++i) {
      int rj = row_sorted[i];
      float v = asrc[rj] + adc;
      v = (v >= 0.f) ? v : 0.2f * v;
      float wj = expf(v - m) * inv;
      unsigned u = ((const unsigned*)(Whb + (size_t)rj * 128))[lane];
      ax += wj * bf_lo(u); ay += wj * bf_hi(u);
    }
  }

  ax = ax > 0.f ? ax : expm1f(ax);
  ay = ay > 0.f ? ay : expm1f(ay);
  ((float2*)out)[(size_t)node * 64 + lane] = make_float2(ax, ay);
}

extern "C" void kernel_launch(void* const* d_in, const int* in_sizes, int n_in,
                              void* d_out, int out_size, void* d_ws, size_t ws_size,
                              hipStream_t stream) {
  const float* h = (const float*)d_in[0];
  const void* ei = d_in[1];
  const float* W = (const float*)d_in[2];
  const float* a = (const float*)d_in[3];
  int N = in_sizes[0] / 128;
  int E = in_sizes[1] / 2;
  float* out = (float*)d_out;

  // workspace layout:
  // Whb[N*128 u16] | asrc[N] f32 | adst[N] f32 | bucket_count[256] | done[1]+pad |
  // bcur[256] | bucket_base[257]+pad | rowptr[N+1] | bin_buf[E] u32 | packed[E] u32 |
  // row_sorted[E] u16
  ushort* Whb = (ushort*)d_ws;
  float* asrc = (float*)(Whb + (size_t)N * 128);
  float* adst = asrc + N;
  int* bucket_count = (int*)(adst + N);
  int* done = bucket_count + MAXB;
  int* bcur = done + 4;
  int* bucket_base = bcur + MAXB;
  int* rowptr = bucket_base + MAXB + 4;
  unsigned* bin_buf = (unsigned*)(rowptr + N + 1);
  unsigned* packed = bin_buf + E;
  ushort* row_sorted = (ushort*)(packed + E);

  int nbuckets = (N + MAXB - 1) >> BSHIFT;
  const int HBLOCKS = 256;

  zero_k<<<1, 256, 0, stream>>>(bucket_count, done);
  histB_k<<<HBLOCKS, 256, 0, stream>>>(ei, E, packed, bucket_count, done, bcur, bucket_base, HBLOCKS);
  gemm_wh<<<(N + 63) / 64, 256, 0, stream>>>(h, W, a, Whb, asrc, adst, N);
  bin_k<<<(E + TILE - 1) / TILE, 1024, 0, stream>>>(packed, bcur, bin_buf, E);
  perm3_k<<<nbuckets, 1024, 0, stream>>>(bin_buf, bucket_base, rowptr, row_sorted, N, nbuckets);
  softagg_k<<<(N + 3) / 4, 256, 0, stream>>>(rowptr, row_sorted, asrc, adst, Whb, out, N);
}

// Round 11
// 94.425 us; speedup vs baseline: 1.2402x; 1.2402x over previous
//
#include <hip/hip_runtime.h>
#include <math.h>

#define NEG_BIG -1.0e30f
#define BSHIFT 8                 // bucket = 256 target-node ids
#define MAXB 256

typedef __attribute__((ext_vector_type(8))) short short8v;   // 8 bf16
typedef __attribute__((ext_vector_type(4))) float f32x4;

__device__ __forceinline__ ushort f2bf(float f) {
  unsigned u = __float_as_uint(f);
  unsigned r = (u + 0x7fffu + ((u >> 16) & 1u)) >> 16;  // round-to-nearest-even
  return (ushort)r;
}
__device__ __forceinline__ float bf_lo(unsigned u) { return __uint_as_float(u << 16); }
__device__ __forceinline__ float bf_hi(unsigned u) { return __uint_as_float(u & 0xffff0000u); }

// ---------- W pack (bf16 MFMA B-fragment order) + zero bucket_count/done ----------
// Fragment slot j = ((kk*8 + n0)*64 + lane)*8 + i holds W[kk*32 + (lane>>4)*8 + i][n0*16 + (lane&15)]
__global__ void wprep_k(const float* __restrict__ W, ushort* __restrict__ Wbf,
                        int* __restrict__ bucket_count, int* __restrict__ done) {
  int j = blockIdx.x * blockDim.x + threadIdx.x;
  if (j < MAXB) bucket_count[j] = 0;
  if (j == 0) *done = 0;
  if (j >= 128 * 128) return;
  int i = j & 7;
  int l = (j >> 3) & 63;
  int n0 = (j >> 9) & 7;
  int kk = j >> 12;
  int k = kk * 32 + ((l >> 4) & 3) * 8 + i;
  int n = n0 * 16 + (l & 15);
  Wbf[j] = f2bf(W[k * 128 + n]);
}

// ---------- convert + pack (col<<16)|row + LDS bucket histogram; last block scans ----------
// NOTE: requires N < 65536; N = 50000 here.
__global__ __launch_bounds__(256) void histB_k(const void* __restrict__ ei, int E,
                                               unsigned* __restrict__ packed,
                                               int* __restrict__ bucket_count,
                                               int* __restrict__ done,
                                               int* __restrict__ bcur,
                                               int* __restrict__ bucket_base, int nblocks) {
  __shared__ int lh[MAXB];
  __shared__ int wsum[4];
  __shared__ int last;
  int tid = (int)threadIdx.x;
  lh[tid] = 0;
  __syncthreads();

  const int* p32 = (const int*)ei;
  bool is64 = true;
#pragma unroll
  for (int i = 0; i < 32; ++i) is64 = is64 && (p32[2 * i + 1] == 0);
  const long long* p64 = (const long long*)ei;
  int stride = gridDim.x * 256;
  for (int e = blockIdx.x * 256 + tid; e < E; e += stride) {
    int r, c;
    if (is64) { r = (int)p64[e]; c = (int)p64[E + e]; }
    else      { r = p32[e];      c = p32[E + e]; }
    packed[e] = ((unsigned)c << 16) | (unsigned)r;
    atomicAdd(&lh[c >> BSHIFT], 1);
  }
  __syncthreads();
  if (lh[tid]) atomicAdd(&bucket_count[tid], lh[tid]);
  __syncthreads();               // RACE FIX: all of this block's adds complete...
  if (tid == 0) {
    __threadfence();             // ...and are device-visible before we signal
    int old = atomicAdd(done, 1);
    last = (old == nblocks - 1);
  }
  __syncthreads();
  if (!last) return;
  __threadfence();               // acquire: all blocks' bucket_count updates visible

  // scan bucket_count[256] (4 waves)
  int lane = tid & 63, wid = tid >> 6;
  int v = atomicAdd(&bucket_count[tid], 0);
  int x = v;
#pragma unroll
  for (int off = 1; off < 64; off <<= 1) {
    int t = __shfl_up(x, off);
    if (lane >= off) x += t;
  }
  if (lane == 63) wsum[wid] = x;
  __syncthreads();
  int woff = 0;
  for (int w = 0; w < wid; ++w) woff += wsum[w];
  int excl = woff + x - v;
  bcur[tid] = excl;
  bucket_base[tid] = excl;
  if (tid == 255) bucket_base[256] = excl + v;
}

// ---------- Wh = h @ W via MFMA bf16 (zero LDS) -> bf16 Whb + fused alpha ----------
// k-map (applied identically to A and B, so result is layout-invariant):
//   k = kk*32 + lg*8 + i,  lane l = lg*16 + lm
__global__ __launch_bounds__(256) void gemm_wh(const float* __restrict__ h,
                                               const ushort* __restrict__ Wbf,
                                               const float* __restrict__ a,
                                               ushort* __restrict__ Whb,
                                               float* __restrict__ asrc,
                                               float* __restrict__ adst, int N) {
  int tid = (int)threadIdx.x;
  int w = tid >> 6;
  int l = tid & 63;
  int lg = l >> 4;
  int lm = l & 15;
  int r0 = blockIdx.x * 64 + 16 * w;
  const short8v* Wb8 = (const short8v*)Wbf;

  float as_v[8], ad_v[8];
#pragma unroll
  for (int n0 = 0; n0 < 8; ++n0) {
    as_v[n0] = a[n0 * 16 + lm];
    ad_v[n0] = a[128 + n0 * 16 + lm];
  }

  f32x4 acc[8];
#pragma unroll
  for (int n0 = 0; n0 < 8; ++n0) acc[n0] = (f32x4){0.f, 0.f, 0.f, 0.f};

  int arow = r0 + lm;
  const float* hrow = h + (size_t)arow * 128;
  bool rok = (arow < N);

#pragma unroll
  for (int kk = 0; kk < 4; ++kk) {
    short8v av;
    if (rok) {
      const float4* hp = (const float4*)(hrow + kk * 32 + lg * 8);
      float4 x0 = hp[0], x1 = hp[1];
      av[0] = (short)f2bf(x0.x); av[1] = (short)f2bf(x0.y);
      av[2] = (short)f2bf(x0.z); av[3] = (short)f2bf(x0.w);
      av[4] = (short)f2bf(x1.x); av[5] = (short)f2bf(x1.y);
      av[6] = (short)f2bf(x1.z); av[7] = (short)f2bf(x1.w);
    } else {
      av = (short8v){0, 0, 0, 0, 0, 0, 0, 0};
    }
#pragma unroll
    for (int n0 = 0; n0 < 8; ++n0) {
      short8v bv = Wb8[(kk * 8 + n0) * 64 + l];
      acc[n0] = __builtin_amdgcn_mfma_f32_16x16x32_bf16(av, bv, acc[n0], 0, 0, 0);
    }
  }

  // store Whb (bf16). D layout: col = n0*16+lm, local row = lg*4+reg
#pragma unroll
  for (int reg = 0; reg < 4; ++reg) {
    int r = r0 + lg * 4 + reg;
    if (r < N) {
      ushort* dst = Whb + (size_t)r * 128;
#pragma unroll
      for (int n0 = 0; n0 < 8; ++n0) dst[n0 * 16 + lm] = f2bf(acc[n0][reg]);
    }
  }

  // fused alpha: reduce over the 16 lm lanes
#pragma unroll
  for (int reg = 0; reg < 4; ++reg) {
    float ps = 0.f, pd = 0.f;
#pragma unroll
    for (int n0 = 0; n0 < 8; ++n0) {
      ps += acc[n0][reg] * as_v[n0];
      pd += acc[n0][reg] * ad_v[n0];
    }
#pragma unroll
    for (int off = 1; off < 16; off <<= 1) {
      ps += __shfl_xor(ps, off);
      pd += __shfl_xor(pd, off);
    }
    int r = r0 + lg * 4 + reg;
    if (lm == 0 && r < N) { asrc[r] = ps; adst[r] = pd; }
  }
}

// ---------- phase 1 sort: coarse-bin packed records by col bucket ----------
#define TILE 8192
__global__ __launch_bounds__(1024) void bin_k(const unsigned* __restrict__ packed,
                                              int* __restrict__ bcur,
                                              unsigned* __restrict__ bin_buf, int E) {
  __shared__ int lhist[MAXB];
  __shared__ int lbase[MAXB];
  int tid = (int)threadIdx.x;
  int t0 = blockIdx.x * TILE;

  if (tid < MAXB) lhist[tid] = 0;
  __syncthreads();

  unsigned rec[8];
  int rb[8], rr[8];
#pragma unroll
  for (int k = 0; k < 8; ++k) {
    int i = t0 + tid + k * 1024;
    rb[k] = -1;
    if (i < E) {
      rec[k] = packed[i];
      rb[k] = (int)(rec[k] >> (16 + BSHIFT));
      rr[k] = atomicAdd(&lhist[rb[k]], 1);
    }
  }
  __syncthreads();
  if (tid < MAXB) lbase[tid] = lhist[tid] ? atomicAdd(&bcur[tid], lhist[tid]) : 0;
  __syncthreads();
#pragma unroll
  for (int k = 0; k < 8; ++k) {
    if (rb[k] >= 0) bin_buf[lbase[rb[k]] + rr[k]] = rec[k];
  }
}

// ---------- phase 2 sort: bucket-local col hist+scan -> rowptr + permute ----------
__global__ __launch_bounds__(1024) void perm3_k(const unsigned* __restrict__ bin_buf,
                                                const int* __restrict__ bucket_base,
                                                int* __restrict__ rowptr,
                                                ushort* __restrict__ row_sorted,
                                                int N, int nbuckets) {
  __shared__ int hist[MAXB];
  __shared__ int cur[MAXB];
  __shared__ int wsum[16];
  int b = blockIdx.x;
  int tid = (int)threadIdx.x;
  int c0 = b << BSHIFT;
  int ncol = min(MAXB, N - c0);
  int e0 = bucket_base[b], e1 = bucket_base[b + 1];

  if (tid < MAXB) hist[tid] = 0;
  __syncthreads();
  for (int i = e0 + tid; i < e1; i += 1024) {
    int cl = (int)(bin_buf[i] >> 16) - c0;
    if ((unsigned)cl < (unsigned)MAXB) atomicAdd(&hist[cl], 1);  // defensive bound
  }
  __syncthreads();

  int lane = tid & 63, wid = tid >> 6;
  int v = (tid < MAXB) ? hist[tid] : 0;
  int x = v;
#pragma unroll
  for (int off = 1; off < 64; off <<= 1) {
    int t = __shfl_up(x, off);
    if (lane >= off) x += t;
  }
  if (lane == 63) wsum[wid] = x;
  __syncthreads();
  if (tid < MAXB) {
    int woff = 0;
    for (int w = 0; w < wid; ++w) woff += wsum[w];
    int excl = woff + x - v;
    cur[tid] = e0 + excl;
    if (tid < ncol) rowptr[c0 + tid] = e0 + excl;
  }
  if (b == nbuckets - 1 && tid == 0) rowptr[N] = e1;
  __syncthreads();

  for (int i = e0 + tid; i < e1; i += 1024) {
    unsigned rec = bin_buf[i];
    int cl = (int)(rec >> 16) - c0;
    if ((unsigned)cl < (unsigned)MAXB) {
      int p = atomicAdd(&cur[cl], 1);
      row_sorted[p] = (ushort)(rec & 0xffffu);
    }
  }
}

// ---------- fused softmax + aggregation + ELU (one wave per node, no LDS) ----------
__global__ __launch_bounds__(256) void softagg_k(const int* __restrict__ rowptr,
                                                 const ushort* __restrict__ row_sorted,
                                                 const float* __restrict__ asrc,
                                                 const float* __restrict__ adst,
                                                 const ushort* __restrict__ Whb,
                                                 float* __restrict__ out, int N) {
  int node = blockIdx.x * 4 + ((int)threadIdx.x >> 6);
  if (node >= N) return;
  int lane = (int)threadIdx.x & 63;
  int beg = rowptr[node], end = rowptr[node + 1];
  int deg = end - beg;
  float adc = adst[node];
  float ax = 0.f, ay = 0.f;

  if (deg <= 64) {
    // fast path: one edge per lane, softmax entirely in registers
    int r = 0;
    float v = NEG_BIG;
    if (lane < deg) {
      r = row_sorted[beg + lane];
      v = asrc[r] + adc;
      v = (v >= 0.f) ? v : 0.2f * v;
    }
    float m = v;
#pragma unroll
    for (int off = 32; off > 0; off >>= 1) m = fmaxf(m, __shfl_xor(m, off));
    float e = (lane < deg) ? expf(v - m) : 0.f;
    float s = e;
#pragma unroll
    for (int off = 32; off > 0; off >>= 1) s += __shfl_xor(s, off);
    float w = e / (s + 1e-16f);

    // phase 2: lanes become features; pull (w_j, r_j) from lane j, 8-deep
    int j = 0;
    for (; j + 7 < deg; j += 8) {
      float wv[8];
      int rv[8];
#pragma unroll
      for (int q = 0; q < 8; ++q) { wv[q] = __shfl(w, j + q); rv[q] = __shfl(r, j + q); }
      unsigned u[8];
#pragma unroll
      for (int q = 0; q < 8; ++q) u[q] = ((const unsigned*)(Whb + (size_t)rv[q] * 128))[lane];
#pragma unroll
      for (int q = 0; q < 8; ++q) { ax += wv[q] * bf_lo(u[q]); ay += wv[q] * bf_hi(u[q]); }
    }
    for (; j < deg; ++j) {
      float wj = __shfl(w, j);
      int rj = __shfl(r, j);
      unsigned u = ((const unsigned*)(Whb + (size_t)rj * 128))[lane];
      ax += wj * bf_lo(u); ay += wj * bf_hi(u);
    }
  } else {
    // slow path (deg > 64): online softmax + recompute weights
    float m = NEG_BIG, s = 0.f;
    for (int i = beg + lane; i < end; i += 64) {
      float v = asrc[row_sorted[i]] + adc;
      v = (v >= 0.f) ? v : 0.2f * v;
      if (v > m) { s = s * expf(m - v) + 1.f; m = v; }
      else       { s += expf(v - m); }
    }
#pragma unroll
    for (int off = 32; off > 0; off >>= 1) {
      float mo = __shfl_xor(m, off);
      float so = __shfl_xor(s, off);
      float M = fmaxf(m, mo);
      s = s * expf(m - M) + so * expf(mo - M);
      m = M;
    }
    float inv = 1.f / (s + 1e-16f);
    for (int i = beg; i < end; ++i) {
      int rj = row_sorted[i];
      float v = asrc[rj] + adc;
      v = (v >= 0.f) ? v : 0.2f * v;
      float wj = expf(v - m) * inv;
      unsigned u = ((const unsigned*)(Whb + (size_t)rj * 128))[lane];
      ax += wj * bf_lo(u); ay += wj * bf_hi(u);
    }
  }

  ax = ax > 0.f ? ax : expm1f(ax);
  ay = ay > 0.f ? ay : expm1f(ay);
  ((float2*)out)[(size_t)node * 64 + lane] = make_float2(ax, ay);
}

extern "C" void kernel_launch(void* const* d_in, const int* in_sizes, int n_in,
                              void* d_out, int out_size, void* d_ws, size_t ws_size,
                              hipStream_t stream) {
  const float* h = (const float*)d_in[0];
  const void* ei = d_in[1];
  const float* W = (const float*)d_in[2];
  const float* a = (const float*)d_in[3];
  int N = in_sizes[0] / 128;
  int E = in_sizes[1] / 2;
  float* out = (float*)d_out;

  // workspace layout:
  // Whb[N*128 u16] | asrc[N] f32 | adst[N] f32 | bucket_count[256] | done[1]+pad |
  // bcur[256] | bucket_base[257]+pad | rowptr[N+1] | bin_buf[E] u32 | packed[E] u32 |
  // row_sorted[E] u16 | Wbf[16384] u16
  ushort* Whb = (ushort*)d_ws;
  float* asrc = (float*)(Whb + (size_t)N * 128);
  float* adst = asrc + N;
  int* bucket_count = (int*)(adst + N);
  int* done = bucket_count + MAXB;
  int* bcur = done + 4;
  int* bucket_base = bcur + MAXB;
  int* rowptr = bucket_base + MAXB + 4;
  unsigned* bin_buf = (unsigned*)(rowptr + N + 1);
  unsigned* packed = bin_buf + E;
  ushort* row_sorted = (ushort*)(packed + E);
  ushort* Wbf = row_sorted + E;

  int nbuckets = (N + MAXB - 1) >> BSHIFT;
  const int HBLOCKS = 256;

  wprep_k<<<64, 256, 0, stream>>>(W, Wbf, bucket_count, done);
  histB_k<<<HBLOCKS, 256, 0, stream>>>(ei, E, packed, bucket_count, done, bcur, bucket_base, HBLOCKS);
  gemm_wh<<<(N + 63) / 64, 256, 0, stream>>>(h, Wbf, a, Whb, asrc, adst, N);
  bin_k<<<(E + TILE - 1) / TILE, 1024, 0, stream>>>(packed, bcur, bin_buf, E);
  perm3_k<<<nbuckets, 1024, 0, stream>>>(bin_buf, bucket_base, rowptr, row_sorted, N, nbuckets);
  softagg_k<<<(N + 3) / 4, 256, 0, stream>>>(rowptr, row_sorted, asrc, adst, Whb, out, N);
}

// Round 12
// 93.491 us; speedup vs baseline: 1.2525x; 1.0100x over previous
//
#include <hip/hip_runtime.h>
#include <math.h>

#define NEG_BIG -1.0e30f
#define BSHIFT 8                 // bucket = 256 target-node ids
#define MAXB 256

typedef __attribute__((ext_vector_type(8))) short short8v;   // 8 bf16
typedef __attribute__((ext_vector_type(4))) float f32x4;

__device__ __forceinline__ ushort f2bf(float f) {
  unsigned u = __float_as_uint(f);
  unsigned r = (u + 0x7fffu + ((u >> 16) & 1u)) >> 16;  // round-to-nearest-even
  return (ushort)r;
}
__device__ __forceinline__ float bf_lo(unsigned u) { return __uint_as_float(u << 16); }
__device__ __forceinline__ float bf_hi(unsigned u) { return __uint_as_float(u & 0xffff0000u); }

// ---------- W pack (bf16 MFMA B-fragment order) + zero bucket_count/done ----------
// Fragment slot j = ((kk*8 + n0)*64 + lane)*8 + i holds W[kk*32 + (lane>>4)*8 + i][n0*16 + (lane&15)]
__global__ void wprep_k(const float* __restrict__ W, ushort* __restrict__ Wbf,
                        int* __restrict__ bucket_count, int* __restrict__ done) {
  int j = blockIdx.x * blockDim.x + threadIdx.x;
  if (j < MAXB) bucket_count[j] = 0;
  if (j == 0) *done = 0;
  if (j >= 128 * 128) return;
  int i = j & 7;
  int l = (j >> 3) & 63;
  int n0 = (j >> 9) & 7;
  int kk = j >> 12;
  int k = kk * 32 + ((l >> 4) & 3) * 8 + i;
  int n = n0 * 16 + (l & 15);
  Wbf[j] = f2bf(W[k * 128 + n]);
}

// ---------- convert + pack (col<<16)|row + LDS bucket histogram; last block scans ----------
// NOTE: requires N < 65536; N = 50000 here.
__global__ __launch_bounds__(256) void histB_k(const void* __restrict__ ei, int E,
                                               unsigned* __restrict__ packed,
                                               int* __restrict__ bucket_count,
                                               int* __restrict__ done,
                                               int* __restrict__ bcur,
                                               int* __restrict__ bucket_base, int nblocks) {
  __shared__ int lh[MAXB];
  __shared__ int wsum[4];
  __shared__ int last;
  int tid = (int)threadIdx.x;
  lh[tid] = 0;
  __syncthreads();

  const int* p32 = (const int*)ei;
  bool is64 = true;
#pragma unroll
  for (int i = 0; i < 32; ++i) is64 = is64 && (p32[2 * i + 1] == 0);
  const long long* p64 = (const long long*)ei;
  int stride = gridDim.x * 256;
  for (int e = blockIdx.x * 256 + tid; e < E; e += stride) {
    int r, c;
    if (is64) { r = (int)p64[e]; c = (int)p64[E + e]; }
    else      { r = p32[e];      c = p32[E + e]; }
    packed[e] = ((unsigned)c << 16) | (unsigned)r;
    atomicAdd(&lh[c >> BSHIFT], 1);
  }
  __syncthreads();
  if (lh[tid]) atomicAdd(&bucket_count[tid], lh[tid]);
  __syncthreads();               // all of this block's adds complete...
  if (tid == 0) {
    __threadfence();             // ...and are device-visible before we signal
    int old = atomicAdd(done, 1);
    last = (old == nblocks - 1);
  }
  __syncthreads();
  if (!last) return;
  __threadfence();               // acquire

  int lane = tid & 63, wid = tid >> 6;
  int v = atomicAdd(&bucket_count[tid], 0);
  int x = v;
#pragma unroll
  for (int off = 1; off < 64; off <<= 1) {
    int t = __shfl_up(x, off);
    if (lane >= off) x += t;
  }
  if (lane == 63) wsum[wid] = x;
  __syncthreads();
  int woff = 0;
  for (int w = 0; w < wid; ++w) woff += wsum[w];
  int excl = woff + x - v;
  bcur[tid] = excl;
  bucket_base[tid] = excl;
  if (tid == 255) bucket_base[256] = excl + v;
}

// ---------- Wh = h @ W via MFMA bf16 (zero LDS) -> permuted-layout Whb + fused alpha ----------
// k-map (applied identically to A and B -> result layout-invariant): k = kk*32 + lg*8 + i
// Whb PERMUTED row layout: Whb[r][lm*8 + n0] holds true col (n0*16 + lm).
__global__ __launch_bounds__(256) void gemm_wh(const float* __restrict__ h,
                                               const ushort* __restrict__ Wbf,
                                               const float* __restrict__ a,
                                               ushort* __restrict__ Whb,
                                               float* __restrict__ asrc,
                                               float* __restrict__ adst, int N) {
  int tid = (int)threadIdx.x;
  int w = tid >> 6;
  int l = tid & 63;
  int lg = l >> 4;
  int lm = l & 15;
  int r0 = blockIdx.x * 64 + 16 * w;
  const short8v* Wb8 = (const short8v*)Wbf;

  float as_v[8], ad_v[8];
#pragma unroll
  for (int n0 = 0; n0 < 8; ++n0) {
    as_v[n0] = a[n0 * 16 + lm];
    ad_v[n0] = a[128 + n0 * 16 + lm];
  }

  f32x4 acc[8];
#pragma unroll
  for (int n0 = 0; n0 < 8; ++n0) acc[n0] = (f32x4){0.f, 0.f, 0.f, 0.f};

  int arow = r0 + lm;
  const float* hrow = h + (size_t)arow * 128;
  bool rok = (arow < N);

#pragma unroll
  for (int kk = 0; kk < 4; ++kk) {
    short8v av;
    if (rok) {
      const float4* hp = (const float4*)(hrow + kk * 32 + lg * 8);
      float4 x0 = hp[0], x1 = hp[1];
      av[0] = (short)f2bf(x0.x); av[1] = (short)f2bf(x0.y);
      av[2] = (short)f2bf(x0.z); av[3] = (short)f2bf(x0.w);
      av[4] = (short)f2bf(x1.x); av[5] = (short)f2bf(x1.y);
      av[6] = (short)f2bf(x1.z); av[7] = (short)f2bf(x1.w);
    } else {
      av = (short8v){0, 0, 0, 0, 0, 0, 0, 0};
    }
#pragma unroll
    for (int n0 = 0; n0 < 8; ++n0) {
      short8v bv = Wb8[(kk * 8 + n0) * 64 + l];
      acc[n0] = __builtin_amdgcn_mfma_f32_16x16x32_bf16(av, bv, acc[n0], 0, 0, 0);
    }
  }

  // store Whb (bf16), PERMUTED layout: one 16B vector store per reg-row.
  // D layout: true col = n0*16+lm, local row = lg*4+reg -> slot lm*8+n0.
#pragma unroll
  for (int reg = 0; reg < 4; ++reg) {
    int r = r0 + lg * 4 + reg;
    if (r < N) {
      short8v pk;
#pragma unroll
      for (int n0 = 0; n0 < 8; ++n0) pk[n0] = (short)f2bf(acc[n0][reg]);
      *(short8v*)(Whb + (size_t)r * 128 + lm * 8) = pk;
    }
  }

  // fused alpha: reduce over the 16 lm lanes
#pragma unroll
  for (int reg = 0; reg < 4; ++reg) {
    float ps = 0.f, pd = 0.f;
#pragma unroll
    for (int n0 = 0; n0 < 8; ++n0) {
      ps += acc[n0][reg] * as_v[n0];
      pd += acc[n0][reg] * ad_v[n0];
    }
#pragma unroll
    for (int off = 1; off < 16; off <<= 1) {
      ps += __shfl_xor(ps, off);
      pd += __shfl_xor(pd, off);
    }
    int r = r0 + lg * 4 + reg;
    if (lm == 0 && r < N) { asrc[r] = ps; adst[r] = pd; }
  }
}

// ---------- phase 1 sort: coarse-bin packed records by col bucket ----------
#define TILE 8192
__global__ __launch_bounds__(1024) void bin_k(const unsigned* __restrict__ packed,
                                              int* __restrict__ bcur,
                                              unsigned* __restrict__ bin_buf, int E) {
  __shared__ int lhist[MAXB];
  __shared__ int lbase[MAXB];
  int tid = (int)threadIdx.x;
  int t0 = blockIdx.x * TILE;

  if (tid < MAXB) lhist[tid] = 0;
  __syncthreads();

  unsigned rec[8];
  int rb[8], rr[8];
#pragma unroll
  for (int k = 0; k < 8; ++k) {
    int i = t0 + tid + k * 1024;
    rb[k] = -1;
    if (i < E) {
      rec[k] = packed[i];
      rb[k] = (int)(rec[k] >> (16 + BSHIFT));
      rr[k] = atomicAdd(&lhist[rb[k]], 1);
    }
  }
  __syncthreads();
  if (tid < MAXB) lbase[tid] = lhist[tid] ? atomicAdd(&bcur[tid], lhist[tid]) : 0;
  __syncthreads();
#pragma unroll
  for (int k = 0; k < 8; ++k) {
    if (rb[k] >= 0) bin_buf[lbase[rb[k]] + rr[k]] = rec[k];
  }
}

// ---------- phase 2 sort: bucket-local col hist+scan -> rowptr + permute ----------
__global__ __launch_bounds__(1024) void perm3_k(const unsigned* __restrict__ bin_buf,
                                                const int* __restrict__ bucket_base,
                                                int* __restrict__ rowptr,
                                                ushort* __restrict__ row_sorted,
                                                int N, int nbuckets) {
  __shared__ int hist[MAXB];
  __shared__ int cur[MAXB];
  __shared__ int wsum[16];
  int b = blockIdx.x;
  int tid = (int)threadIdx.x;
  int c0 = b << BSHIFT;
  int ncol = min(MAXB, N - c0);
  int e0 = bucket_base[b], e1 = bucket_base[b + 1];

  if (tid < MAXB) hist[tid] = 0;
  __syncthreads();
  for (int i = e0 + tid; i < e1; i += 1024) {
    int cl = (int)(bin_buf[i] >> 16) - c0;
    if ((unsigned)cl < (unsigned)MAXB) atomicAdd(&hist[cl], 1);  // defensive bound
  }
  __syncthreads();

  int lane = tid & 63, wid = tid >> 6;
  int v = (tid < MAXB) ? hist[tid] : 0;
  int x = v;
#pragma unroll
  for (int off = 1; off < 64; off <<= 1) {
    int t = __shfl_up(x, off);
    if (lane >= off) x += t;
  }
  if (lane == 63) wsum[wid] = x;
  __syncthreads();
  if (tid < MAXB) {
    int woff = 0;
    for (int w = 0; w < wid; ++w) woff += wsum[w];
    int excl = woff + x - v;
    cur[tid] = e0 + excl;
    if (tid < ncol) rowptr[c0 + tid] = e0 + excl;
  }
  if (b == nbuckets - 1 && tid == 0) rowptr[N] = e1;
  __syncthreads();

  for (int i = e0 + tid; i < e1; i += 1024) {
    unsigned rec = bin_buf[i];
    int cl = (int)(rec >> 16) - c0;
    if ((unsigned)cl < (unsigned)MAXB) {
      int p = atomicAdd(&cur[cl], 1);
      row_sorted[p] = (ushort)(rec & 0xffffu);
    }
  }
}

// ---------- fused softmax + aggregation + ELU (one wave per node, no LDS) ----------
// Whb rows are PERMUTED (slot s = lm*8+n0 -> true col n0*16+lm). Lane j's u32 holds
// slots {2j, 2j+1} -> true cols c0 = 32*(j&3) + (j>>2) and c0+16.
__global__ __launch_bounds__(256) void softagg_k(const int* __restrict__ rowptr,
                                                 const ushort* __restrict__ row_sorted,
                                                 const float* __restrict__ asrc,
                                                 const float* __restrict__ adst,
                                                 const ushort* __restrict__ Whb,
                                                 float* __restrict__ out, int N) {
  int node = blockIdx.x * 4 + ((int)threadIdx.x >> 6);
  if (node >= N) return;
  int lane = (int)threadIdx.x & 63;
  int beg = rowptr[node], end = rowptr[node + 1];
  int deg = end - beg;
  float adc = adst[node];
  float ax = 0.f, ay = 0.f;

  if (deg <= 64) {
    // fast path: one edge per lane, softmax entirely in registers
    int r = 0;
    float v = NEG_BIG;
    if (lane < deg) {
      r = row_sorted[beg + lane];
      v = asrc[r] + adc;
      v = (v >= 0.f) ? v : 0.2f * v;
    }
    float m = v;
#pragma unroll
    for (int off = 32; off > 0; off >>= 1) m = fmaxf(m, __shfl_xor(m, off));
    float e = (lane < deg) ? expf(v - m) : 0.f;
    float s = e;
#pragma unroll
    for (int off = 32; off > 0; off >>= 1) s += __shfl_xor(s, off);
    float w = e / (s + 1e-16f);

    // phase 2: lanes become features; pull (w_j, r_j) from lane j, 8-deep
    int j = 0;
    for (; j + 7 < deg; j += 8) {
      float wv[8];
      int rv[8];
#pragma unroll
      for (int q = 0; q < 8; ++q) { wv[q] = __shfl(w, j + q); rv[q] = __shfl(r, j + q); }
      unsigned u[8];
#pragma unroll
      for (int q = 0; q < 8; ++q) u[q] = ((const unsigned*)(Whb + (size_t)rv[q] * 128))[lane];
#pragma unroll
      for (int q = 0; q < 8; ++q) { ax += wv[q] * bf_lo(u[q]); ay += wv[q] * bf_hi(u[q]); }
    }
    for (; j < deg; ++j) {
      float wj = __shfl(w, j);
      int rj = __shfl(r, j);
      unsigned u = ((const unsigned*)(Whb + (size_t)rj * 128))[lane];
      ax += wj * bf_lo(u); ay += wj * bf_hi(u);
    }
  } else {
    // slow path (deg > 64): online softmax + recompute weights
    float m = NEG_BIG, s = 0.f;
    for (int i = beg + lane; i < end; i += 64) {
      float v = asrc[row_sorted[i]] + adc;
      v = (v >= 0.f) ? v : 0.2f * v;
      if (v > m) { s = s * expf(m - v) + 1.f; m = v; }
      else       { s += expf(v - m); }
    }
#pragma unroll
    for (int off = 32; off > 0; off >>= 1) {
      float mo = __shfl_xor(m, off);
      float so = __shfl_xor(s, off);
      float M = fmaxf(m, mo);
      s = s * expf(m - M) + so * expf(mo - M);
      m = M;
    }
    float inv = 1.f / (s + 1e-16f);
    for (int i = beg; i < end; ++i) {
      int rj = row_sorted[i];
      float v = asrc[rj] + adc;
      v = (v >= 0.f) ? v : 0.2f * v;
      float wj = expf(v - m) * inv;
      unsigned u = ((const unsigned*)(Whb + (size_t)rj * 128))[lane];
      ax += wj * bf_lo(u); ay += wj * bf_hi(u);
    }
  }

  ax = ax > 0.f ? ax : expm1f(ax);
  ay = ay > 0.f ? ay : expm1f(ay);
  // un-permute on store: lane j -> true cols c0 and c0+16 (contiguous 512B row segment)
  int c0 = ((lane & 3) << 5) + (lane >> 2);
  float* orow = out + (size_t)node * 128;
  orow[c0] = ax;
  orow[c0 + 16] = ay;
}

extern "C" void kernel_launch(void* const* d_in, const int* in_sizes, int n_in,
                              void* d_out, int out_size, void* d_ws, size_t ws_size,
                              hipStream_t stream) {
  const float* h = (const float*)d_in[0];
  const void* ei = d_in[1];
  const float* W = (const float*)d_in[2];
  const float* a = (const float*)d_in[3];
  int N = in_sizes[0] / 128;
  int E = in_sizes[1] / 2;
  float* out = (float*)d_out;

  // workspace layout:
  // Whb[N*128 u16] | asrc[N] f32 | adst[N] f32 | bucket_count[256] | done[1]+pad |
  // bcur[256] | bucket_base[257]+pad | rowptr[N+1] | bin_buf[E] u32 | packed[E] u32 |
  // row_sorted[E] u16 | Wbf[16384] u16
  ushort* Whb = (ushort*)d_ws;
  float* asrc = (float*)(Whb + (size_t)N * 128);
  float* adst = asrc + N;
  int* bucket_count = (int*)(adst + N);
  int* done = bucket_count + MAXB;
  int* bcur = done + 4;
  int* bucket_base = bcur + MAXB;
  int* rowptr = bucket_base + MAXB + 4;
  unsigned* bin_buf = (unsigned*)(rowptr + N + 1);
  unsigned* packed = bin_buf + E;
  ushort* row_sorted = (ushort*)(packed + E);
  ushort* Wbf = row_sorted + E;

  int nbuckets = (N + MAXB - 1) >> BSHIFT;
  const int HBLOCKS = 256;

  wprep_k<<<64, 256, 0, stream>>>(W, Wbf, bucket_count, done);
  histB_k<<<HBLOCKS, 256, 0, stream>>>(ei, E, packed, bucket_count, done, bcur, bucket_base, HBLOCKS);
  gemm_wh<<<(N + 63) / 64, 256, 0, stream>>>(h, Wbf, a, Whb, asrc, adst, N);
  bin_k<<<(E + TILE - 1) / TILE, 1024, 0, stream>>>(packed, bcur, bin_buf, E);
  perm3_k<<<nbuckets, 1024, 0, stream>>>(bin_buf, bucket_base, rowptr, row_sorted, N, nbuckets);
  softagg_k<<<(N + 3) / 4, 256, 0, stream>>>(rowptr, row_sorted, asrc, adst, Whb, out, N);
}

// Round 13
// 90.292 us; speedup vs baseline: 1.2969x; 1.0354x over previous
//
#include <hip/hip_runtime.h>
#include <math.h>

#define NEG_BIG -1.0e30f
#define BSHIFT 8                 // bucket = 256 target-node ids
#define MAXB 256

typedef __attribute__((ext_vector_type(8))) short short8v;   // 8 bf16
typedef __attribute__((ext_vector_type(4))) float f32x4;

__device__ __forceinline__ ushort f2bf(float f) {
  unsigned u = __float_as_uint(f);
  unsigned r = (u + 0x7fffu + ((u >> 16) & 1u)) >> 16;  // round-to-nearest-even
  return (ushort)r;
}
__device__ __forceinline__ float bf_lo(unsigned u) { return __uint_as_float(u << 16); }
__device__ __forceinline__ float bf_hi(unsigned u) { return __uint_as_float(u & 0xffff0000u); }

// ---------- K1: W pack (bf16 MFMA B-fragment order) + zero bucket_count/done ----------
__global__ void wprep_k(const float* __restrict__ W, ushort* __restrict__ Wbf,
                        int* __restrict__ bucket_count, int* __restrict__ done) {
  int j = blockIdx.x * blockDim.x + threadIdx.x;
  if (j < MAXB) bucket_count[j] = 0;
  if (j == 0) *done = 0;
  if (j >= 128 * 128) return;
  int i = j & 7;
  int l = (j >> 3) & 63;
  int n0 = (j >> 9) & 7;
  int kk = j >> 12;
  int k = kk * 32 + ((l >> 4) & 3) * 8 + i;
  int n = n0 * 16 + (l & 15);
  Wbf[j] = f2bf(W[k * 128 + n]);
}

// ---------- K2: fused histB (blocks 0..hblocks-1) ∥ gemm (blocks hblocks..) ----------
// histB: convert + pack (col<<16)|row + bucket histogram; last histB block scans.
// gemm: Wh = h @ W via MFMA bf16 (zero LDS) -> permuted-layout Whb + fused alpha.
// NOTE: requires N < 65536; N = 50000 here.
__global__ __launch_bounds__(256) void hist_gemm_k(
    const void* __restrict__ ei, int E,
    unsigned* __restrict__ packed, int* __restrict__ bucket_count,
    int* __restrict__ done, int* __restrict__ bcur, int* __restrict__ bucket_base,
    int hblocks,
    const float* __restrict__ h, const ushort* __restrict__ Wbf,
    const float* __restrict__ a, ushort* __restrict__ Whb,
    float* __restrict__ asrc, float* __restrict__ adst, int N) {
  __shared__ int lh[MAXB];
  __shared__ int wsum[4];
  __shared__ int last;
  int tid = (int)threadIdx.x;

  if ((int)blockIdx.x < hblocks) {
    // ================= histB body =================
    lh[tid] = 0;
    __syncthreads();

    const int* p32 = (const int*)ei;
    bool is64 = true;
#pragma unroll
    for (int i = 0; i < 32; ++i) is64 = is64 && (p32[2 * i + 1] == 0);
    const long long* p64 = (const long long*)ei;
    int stride = hblocks * 256;
    for (int e = blockIdx.x * 256 + tid; e < E; e += stride) {
      int r, c;
      if (is64) { r = (int)p64[e]; c = (int)p64[E + e]; }
      else      { r = p32[e];      c = p32[E + e]; }
      packed[e] = ((unsigned)c << 16) | (unsigned)r;
      atomicAdd(&lh[c >> BSHIFT], 1);
    }
    __syncthreads();
    if (lh[tid]) atomicAdd(&bucket_count[tid], lh[tid]);
    __syncthreads();               // all of this block's adds issued...
    if (tid == 0) {
      __threadfence();             // ...and device-visible before signaling
      int old = atomicAdd(done, 1);
      last = (old == hblocks - 1);
    }
    __syncthreads();
    if (!last) return;
    __threadfence();               // acquire

    int lane = tid & 63, wid = tid >> 6;
    int v = atomicAdd(&bucket_count[tid], 0);
    int x = v;
#pragma unroll
    for (int off = 1; off < 64; off <<= 1) {
      int t = __shfl_up(x, off);
      if (lane >= off) x += t;
    }
    if (lane == 63) wsum[wid] = x;
    __syncthreads();
    int woff = 0;
    for (int w = 0; w < wid; ++w) woff += wsum[w];
    int excl = woff + x - v;
    bcur[tid] = excl;
    bucket_base[tid] = excl;
    if (tid == 255) bucket_base[256] = excl + v;
    return;
  }

  // ================= gemm body =================
  // k-map (applied identically to A and B -> result layout-invariant): k = kk*32 + lg*8 + i
  // Whb PERMUTED row layout: Whb[r][lm*8 + n0] holds true col (n0*16 + lm).
  int gb = (int)blockIdx.x - hblocks;
  int w = tid >> 6;
  int l = tid & 63;
  int lg = l >> 4;
  int lm = l & 15;
  int r0 = gb * 64 + 16 * w;
  const short8v* Wb8 = (const short8v*)Wbf;

  float as_v[8], ad_v[8];
#pragma unroll
  for (int n0 = 0; n0 < 8; ++n0) {
    as_v[n0] = a[n0 * 16 + lm];
    ad_v[n0] = a[128 + n0 * 16 + lm];
  }

  f32x4 acc[8];
#pragma unroll
  for (int n0 = 0; n0 < 8; ++n0) acc[n0] = (f32x4){0.f, 0.f, 0.f, 0.f};

  int arow = r0 + lm;
  const float* hrow = h + (size_t)arow * 128;
  bool rok = (arow < N);

#pragma unroll
  for (int kk = 0; kk < 4; ++kk) {
    short8v av;
    if (rok) {
      const float4* hp = (const float4*)(hrow + kk * 32 + lg * 8);
      float4 x0 = hp[0], x1 = hp[1];
      av[0] = (short)f2bf(x0.x); av[1] = (short)f2bf(x0.y);
      av[2] = (short)f2bf(x0.z); av[3] = (short)f2bf(x0.w);
      av[4] = (short)f2bf(x1.x); av[5] = (short)f2bf(x1.y);
      av[6] = (short)f2bf(x1.z); av[7] = (short)f2bf(x1.w);
    } else {
      av = (short8v){0, 0, 0, 0, 0, 0, 0, 0};
    }
#pragma unroll
    for (int n0 = 0; n0 < 8; ++n0) {
      short8v bv = Wb8[(kk * 8 + n0) * 64 + l];
      acc[n0] = __builtin_amdgcn_mfma_f32_16x16x32_bf16(av, bv, acc[n0], 0, 0, 0);
    }
  }

  // store Whb (bf16), PERMUTED layout: one 16B vector store per reg-row.
#pragma unroll
  for (int reg = 0; reg < 4; ++reg) {
    int r = r0 + lg * 4 + reg;
    if (r < N) {
      short8v pk;
#pragma unroll
      for (int n0 = 0; n0 < 8; ++n0) pk[n0] = (short)f2bf(acc[n0][reg]);
      *(short8v*)(Whb + (size_t)r * 128 + lm * 8) = pk;
    }
  }

  // fused alpha: reduce over the 16 lm lanes
#pragma unroll
  for (int reg = 0; reg < 4; ++reg) {
    float ps = 0.f, pd = 0.f;
#pragma unroll
    for (int n0 = 0; n0 < 8; ++n0) {
      ps += acc[n0][reg] * as_v[n0];
      pd += acc[n0][reg] * ad_v[n0];
    }
#pragma unroll
    for (int off = 1; off < 16; off <<= 1) {
      ps += __shfl_xor(ps, off);
      pd += __shfl_xor(pd, off);
    }
    int r = r0 + lg * 4 + reg;
    if (lm == 0 && r < N) { asrc[r] = ps; adst[r] = pd; }
  }
}

// ---------- phase 1 sort: coarse-bin packed records by col bucket ----------
#define TILE 8192
__global__ __launch_bounds__(1024) void bin_k(const unsigned* __restrict__ packed,
                                              int* __restrict__ bcur,
                                              unsigned* __restrict__ bin_buf, int E) {
  __shared__ int lhist[MAXB];
  __shared__ int lbase[MAXB];
  int tid = (int)threadIdx.x;
  int t0 = blockIdx.x * TILE;

  if (tid < MAXB) lhist[tid] = 0;
  __syncthreads();

  unsigned rec[8];
  int rb[8], rr[8];
#pragma unroll
  for (int k = 0; k < 8; ++k) {
    int i = t0 + tid + k * 1024;
    rb[k] = -1;
    if (i < E) {
      rec[k] = packed[i];
      rb[k] = (int)(rec[k] >> (16 + BSHIFT));
      rr[k] = atomicAdd(&lhist[rb[k]], 1);
    }
  }
  __syncthreads();
  if (tid < MAXB) lbase[tid] = lhist[tid] ? atomicAdd(&bcur[tid], lhist[tid]) : 0;
  __syncthreads();
#pragma unroll
  for (int k = 0; k < 8; ++k) {
    if (rb[k] >= 0) bin_buf[lbase[rb[k]] + rr[k]] = rec[k];
  }
}

// ---------- phase 2 sort: bucket-local col hist+scan -> rowptr + permute ----------
__global__ __launch_bounds__(1024) void perm3_k(const unsigned* __restrict__ bin_buf,
                                                const int* __restrict__ bucket_base,
                                                int* __restrict__ rowptr,
                                                ushort* __restrict__ row_sorted,
                                                int N, int nbuckets) {
  __shared__ int hist[MAXB];
  __shared__ int cur[MAXB];
  __shared__ int wsum[16];
  int b = blockIdx.x;
  int tid = (int)threadIdx.x;
  int c0 = b << BSHIFT;
  int ncol = min(MAXB, N - c0);
  int e0 = bucket_base[b], e1 = bucket_base[b + 1];

  if (tid < MAXB) hist[tid] = 0;
  __syncthreads();
  for (int i = e0 + tid; i < e1; i += 1024) {
    int cl = (int)(bin_buf[i] >> 16) - c0;
    if ((unsigned)cl < (unsigned)MAXB) atomicAdd(&hist[cl], 1);  // defensive bound
  }
  __syncthreads();

  int lane = tid & 63, wid = tid >> 6;
  int v = (tid < MAXB) ? hist[tid] : 0;
  int x = v;
#pragma unroll
  for (int off = 1; off < 64; off <<= 1) {
    int t = __shfl_up(x, off);
    if (lane >= off) x += t;
  }
  if (lane == 63) wsum[wid] = x;
  __syncthreads();
  if (tid < MAXB) {
    int woff = 0;
    for (int w = 0; w < wid; ++w) woff += wsum[w];
    int excl = woff + x - v;
    cur[tid] = e0 + excl;
    if (tid < ncol) rowptr[c0 + tid] = e0 + excl;
  }
  if (b == nbuckets - 1 && tid == 0) rowptr[N] = e1;
  __syncthreads();

  for (int i = e0 + tid; i < e1; i += 1024) {
    unsigned rec = bin_buf[i];
    int cl = (int)(rec >> 16) - c0;
    if ((unsigned)cl < (unsigned)MAXB) {
      int p = atomicAdd(&cur[cl], 1);
      row_sorted[p] = (ushort)(rec & 0xffffu);
    }
  }
}

// ---------- fused softmax + aggregation + ELU (one wave per node, no LDS) ----------
// Whb rows are PERMUTED (slot s = lm*8+n0 -> true col n0*16+lm). Lane j's u32 holds
// slots {2j, 2j+1} -> true cols c0 = 32*(j&3) + (j>>2) and c0+16.
__global__ __launch_bounds__(256) void softagg_k(const int* __restrict__ rowptr,
                                                 const ushort* __restrict__ row_sorted,
                                                 const float* __restrict__ asrc,
                                                 const float* __restrict__ adst,
                                                 const ushort* __restrict__ Whb,
                                                 float* __restrict__ out, int N) {
  int node = blockIdx.x * 4 + ((int)threadIdx.x >> 6);
  if (node >= N) return;
  int lane = (int)threadIdx.x & 63;
  int beg = rowptr[node], end = rowptr[node + 1];
  int deg = end - beg;
  float adc = adst[node];
  float ax = 0.f, ay = 0.f;

  if (deg <= 64) {
    // fast path: one edge per lane, softmax entirely in registers
    int r = 0;
    float v = NEG_BIG;
    if (lane < deg) {
      r = row_sorted[beg + lane];
      v = asrc[r] + adc;
      v = (v >= 0.f) ? v : 0.2f * v;
    }
    float m = v;
#pragma unroll
    for (int off = 32; off > 0; off >>= 1) m = fmaxf(m, __shfl_xor(m, off));
    float e = (lane < deg) ? __expf(v - m) : 0.f;
    float s = e;
#pragma unroll
    for (int off = 32; off > 0; off >>= 1) s += __shfl_xor(s, off);
    float w = e / (s + 1e-16f);

    // phase 2: lanes become features; pull (w_j, r_j) from lane j, 8-deep
    int j = 0;
    for (; j + 7 < deg; j += 8) {
      float wv[8];
      int rv[8];
#pragma unroll
      for (int q = 0; q < 8; ++q) { wv[q] = __shfl(w, j + q); rv[q] = __shfl(r, j + q); }
      unsigned u[8];
#pragma unroll
      for (int q = 0; q < 8; ++q) u[q] = ((const unsigned*)(Whb + (size_t)rv[q] * 128))[lane];
#pragma unroll
      for (int q = 0; q < 8; ++q) { ax += wv[q] * bf_lo(u[q]); ay += wv[q] * bf_hi(u[q]); }
    }
    for (; j < deg; ++j) {
      float wj = __shfl(w, j);
      int rj = __shfl(r, j);
      unsigned u = ((const unsigned*)(Whb + (size_t)rj * 128))[lane];
      ax += wj * bf_lo(u); ay += wj * bf_hi(u);
    }
  } else {
    // slow path (deg > 64): online softmax + recompute weights
    float m = NEG_BIG, s = 0.f;
    for (int i = beg + lane; i < end; i += 64) {
      float v = asrc[row_sorted[i]] + adc;
      v = (v >= 0.f) ? v : 0.2f * v;
      if (v > m) { s = s * __expf(m - v) + 1.f; m = v; }
      else       { s += __expf(v - m); }
    }
#pragma unroll
    for (int off = 32; off > 0; off >>= 1) {
      float mo = __shfl_xor(m, off);
      float so = __shfl_xor(s, off);
      float M = fmaxf(m, mo);
      s = s * __expf(m - M) + so * __expf(mo - M);
      m = M;
    }
    float inv = 1.f / (s + 1e-16f);
    for (int i = beg; i < end; ++i) {
      int rj = row_sorted[i];
      float v = asrc[rj] + adc;
      v = (v >= 0.f) ? v : 0.2f * v;
      float wj = __expf(v - m) * inv;
      unsigned u = ((const unsigned*)(Whb + (size_t)rj * 128))[lane];
      ax += wj * bf_lo(u); ay += wj * bf_hi(u);
    }
  }

  ax = ax > 0.f ? ax : expm1f(ax);
  ay = ay > 0.f ? ay : expm1f(ay);
  // un-permute on store: lane j -> true cols c0 and c0+16 (contiguous 512B row segment)
  int c0 = ((lane & 3) << 5) + (lane >> 2);
  float* orow = out + (size_t)node * 128;
  orow[c0] = ax;
  orow[c0 + 16] = ay;
}

extern "C" void kernel_launch(void* const* d_in, const int* in_sizes, int n_in,
                              void* d_out, int out_size, void* d_ws, size_t ws_size,
                              hipStream_t stream) {
  const float* h = (const float*)d_in[0];
  const void* ei = d_in[1];
  const float* W = (const float*)d_in[2];
  const float* a = (const float*)d_in[3];
  int N = in_sizes[0] / 128;
  int E = in_sizes[1] / 2;
  float* out = (float*)d_out;

  // workspace layout:
  // Whb[N*128 u16] | asrc[N] f32 | adst[N] f32 | bucket_count[256] | done[1]+pad |
  // bcur[256] | bucket_base[257]+pad | rowptr[N+1] | bin_buf[E] u32 | packed[E] u32 |
  // row_sorted[E] u16 | Wbf[16384] u16
  ushort* Whb = (ushort*)d_ws;
  float* asrc = (float*)(Whb + (size_t)N * 128);
  float* adst = asrc + N;
  int* bucket_count = (int*)(adst + N);
  int* done = bucket_count + MAXB;
  int* bcur = done + 4;
  int* bucket_base = bcur + MAXB;
  int* rowptr = bucket_base + MAXB + 4;
  unsigned* bin_buf = (unsigned*)(rowptr + N + 1);
  unsigned* packed = bin_buf + E;
  ushort* row_sorted = (ushort*)(packed + E);
  ushort* Wbf = row_sorted + E;

  int nbuckets = (N + MAXB - 1) >> BSHIFT;
  const int HBLOCKS = 256;
  int gblocks = (N + 63) / 64;

  wprep_k<<<64, 256, 0, stream>>>(W, Wbf, bucket_count, done);
  hist_gemm_k<<<HBLOCKS + gblocks, 256, 0, stream>>>(
      ei, E, packed, bucket_count, done, bcur, bucket_base, HBLOCKS,
      h, Wbf, a, Whb, asrc, adst, N);
  bin_k<<<(E + TILE - 1) / TILE, 1024, 0, stream>>>(packed, bcur, bin_buf, E);
  perm3_k<<<nbuckets, 1024, 0, stream>>>(bin_buf, bucket_base, rowptr, row_sorted, N, nbuckets);
  softagg_k<<<(N + 3) / 4, 256, 0, stream>>>(rowptr, row_sorted, asrc, adst, Whb, out, N);
}